// Round 1
// baseline (96.026 us; speedup 1.0000x reference)
//
#include <hip/hip_runtime.h>
#include <math.h>

#define EPSF 1e-6f
constexpr int Bn  = 32;
constexpr int CLS = 16;
constexpr int DST = 8;
constexpr int Cc  = 64, Hh = 16, Wd = 16;
constexpr int CHW  = Cc * Hh * Wd;   // 16384
constexpr int CHW2 = 2 * CHW;        // 32768
constexpr int CHW4 = 4 * CHW;        // 65536
constexpr int KCHUNK = 64;           // k2 chunks per class

// fast log-sigmoid: -log(1+exp(-x)) = min(x,0) - log(1+exp(-|x|))
__device__ __forceinline__ float fls(float x) {
    float t = __expf(-fabsf(x));
    return fminf(x, 0.0f) - __logf(1.0f + t);
}

__device__ __forceinline__ float4 ld4(const float* p) { return *(const float4*)p; }
__device__ __forceinline__ void st4(float* p, float4 v) { *(float4*)p = v; }

// ---------------------------------------------------------------------------
// k1: blocks [0,512):   kA — (class, e4-chunk) segment sums, float4.
//     blocks [512,640): lm-precompute — per (d,e4): log_sigmoid of miu, float4.
// ---------------------------------------------------------------------------
__global__ __launch_bounds__(256) void k1(
                   const float* __restrict__ x, const int* __restrict__ labels,
                   const float* __restrict__ X_LEs, const float* __restrict__ X_LEs_xy,
                   const float* __restrict__ X_weights, const float* __restrict__ miu,
                   float* __restrict__ xle_out, float* __restrict__ xy_out,
                   float* __restrict__ lm0a, float* __restrict__ lm1a,
                   float* __restrict__ lm1ea)
{
    if (blockIdx.x >= 512) {
        // ---- lm path: idx over [0, DST*CHW/4) ----
        const int idx = (blockIdx.x - 512) * 256 + threadIdx.x;   // [0, 32768)
        const int d  = idx >> 12;            // / 4096
        const int e4 = (idx & 4095) << 2;    // element offset, multiple of 4
        const float4 m0 = ld4(miu + d * CHW2 + e4);
        const float4 m1 = ld4(miu + d * CHW2 + CHW + e4);
        float4 r0, r1, r1e;
        r0.x = fls(m0.x); r0.y = fls(m0.y); r0.z = fls(m0.z); r0.w = fls(m0.w);
        r1.x = fls(m1.x); r1.y = fls(m1.y); r1.z = fls(m1.z); r1.w = fls(m1.w);
        r1e.x = fls(m1.x + EPSF); r1e.y = fls(m1.y + EPSF);
        r1e.z = fls(m1.z + EPSF); r1e.w = fls(m1.w + EPSF);
        st4(lm0a  + d * CHW + e4, r0);
        st4(lm1a  + d * CHW + e4, r1);
        st4(lm1ea + d * CHW + e4, r1e);
        return;
    }

    // ---- kA path: c = class (block-uniform), e4 over [0, CHW2) step 4 ----
    const int c  = blockIdx.x >> 5;                          // [0,16)
    const int t  = (blockIdx.x & 31) * 256 + threadIdx.x;    // [0, 8192)
    const int e4 = t << 2;                                   // [0, CHW2)

    __shared__ int lab_sh[Bn];
    if (threadIdx.x < Bn) lab_sh[threadIdx.x] = labels[threadIdx.x];
    __syncthreads();

    float4 acc_tm = {0.f,0.f,0.f,0.f}, acc_xy = {0.f,0.f,0.f,0.f};
    float cnt = 0.f;
    for (int b = 0; b < Bn; ++b) {
        if (lab_sh[b] == c) {            // block-uniform: skip loads entirely
            const float4 xt = ld4(x + b * CHW4 + e4);
            const float4 xx = ld4(x + b * CHW4 + CHW2 + e4);
            acc_tm.x += xt.x; acc_tm.y += xt.y; acc_tm.z += xt.z; acc_tm.w += xt.w;
            acc_xy.x += xx.x; acc_xy.y += xx.y; acc_xy.z += xx.z; acc_xy.w += xx.w;
            cnt += 1.0f;
        }
    }

    const float xw = X_weights[c] + cnt;
    const float4 le  = ld4(X_LEs    + c * CHW2 + e4);
    const float4 xy  = ld4(X_LEs_xy + c * CHW2 + e4);
    float4 o1, o2;
    o1.x = (le.x + acc_tm.x) / xw; o1.y = (le.y + acc_tm.y) / xw;
    o1.z = (le.z + acc_tm.z) / xw; o1.w = (le.w + acc_tm.w) / xw;
    o2.x = (xy.x + acc_xy.x) / xw; o2.y = (xy.y + acc_xy.y) / xw;
    o2.z = (xy.z + acc_xy.z) / xw; o2.w = (xy.w + acc_xy.w) / xw;
    st4(xle_out + c * CHW2 + e4, o1);
    st4(xy_out  + c * CHW2 + e4, o2);
}

// ---------------------------------------------------------------------------
// k2: per (c,e): means_theta, log(means_mag+eps); le_norm partials -> block
// reduce in LDS, write 8 unique partials per block. NO atomics. (unchanged)
// ---------------------------------------------------------------------------
__global__ __launch_bounds__(256) void k2(
                   const float* __restrict__ xle_out, const float* __restrict__ miu,
                   const float* __restrict__ sigmas, const float* __restrict__ tao,
                   const float* __restrict__ w1,
                   const float* __restrict__ lm0a, const float* __restrict__ lm1a,
                   const float* __restrict__ lm1ea,
                   float* __restrict__ means_theta, float* __restrict__ lmm_out,
                   float* __restrict__ partials)
{
    const int c     = blockIdx.x >> 6;
    const int chunk = blockIdx.x & 63;
    const int e     = chunk * blockDim.x + threadIdx.x;   // [0, CHW)

    const float sig    = sigmas[c];
    const float sig_sq = sig * sig;

    float w1sqv[DST];
    float ssum = 0.f;
#pragma unroll
    for (int d = 0; d < DST; ++d) { const float t = w1[d]; w1sqv[d] = t * t; ssum += t * t; }
    const float ssum_r = 1.0f / ssum;

    const float xle0 = xle_out[c * CHW2 + e];
    const float xle1 = xle_out[c * CHW2 + CHW + e];   // mag
    const float ls0  = fls(xle0);
    const float ls1  = fls(xle1);
    const float ls1e = fls(xle1 + EPSF);

    float mt = 0.f, mm = 0.f;
    float ln_d[DST];

#pragma unroll
    for (int d = 0; d < DST; ++d) {
        const float ta     = tao[d];
        const float tao_sq = ta * ta;
        const float den_r  = 1.0f / (sig_sq + tao_sq);
        const float a      = tao_sq * den_r;
        const float b      = sig_sq * den_r;
        const float wn     = w1sqv[d] * ssum_r;

        const float m0   = miu[d * CHW2 + e];
        const float lm0  = lm0a [d * CHW + e];
        const float lm1  = lm1a [d * CHW + e];
        const float lm1e = lm1ea[d * CHW + e];

        mt += (xle1 * a + m0 * b) * wn;
        mm += __expf((a * ls1e + b * lm1e) * wn);

        const float d0 = ls0 - lm0, d1 = ls1 - lm1;
        ln_d[d] = d0 * d0 + d1 * d1;
    }

    means_theta[c * CHW + e] = mt;
    lmm_out    [c * CHW + e] = __logf(mm + EPSF);

    __shared__ float sh[4][DST];
    const int wave = threadIdx.x >> 6;
    const int lane = threadIdx.x & 63;
#pragma unroll
    for (int d = 0; d < DST; ++d) {
        float v = ln_d[d];
        v += __shfl_down(v, 32);
        v += __shfl_down(v, 16);
        v += __shfl_down(v, 8);
        v += __shfl_down(v, 4);
        v += __shfl_down(v, 2);
        v += __shfl_down(v, 1);
        if (lane == 0) sh[wave][d] = v;
    }
    __syncthreads();
    if (threadIdx.x < DST) {
        const int d = threadIdx.x;
        const float s = sh[0][d] + sh[1][d] + sh[2][d] + sh[3][d];
        partials[(d * CLS + c) * KCHUNK + chunk] = s;
    }
}

// ---------------------------------------------------------------------------
// k3: blocks [0,256): kD — block owns a 64-element chunk for ALL 32 batches.
//     Class arrays (means_theta, lmm, xy_out x2) for that chunk are staged in
//     16 KB LDS once (4 MB total global reads instead of 128 MB of L2
//     re-reads), then each wave handles one batch b per iteration.
//     block 256:      kC — loss[d], second-stage reduce of partials.
// ---------------------------------------------------------------------------
__global__ __launch_bounds__(256) void k3(
                   const float* __restrict__ x, const float* __restrict__ weight,
                   const float* __restrict__ means_theta, const float* __restrict__ lmm,
                   const float* __restrict__ xy_out,
                   const int* __restrict__ labels, const float* __restrict__ X_weights,
                   const float* __restrict__ sigmas, const float* __restrict__ tao,
                   const float* __restrict__ partials,
                   float* __restrict__ out, float* __restrict__ loss_out)
{
    if (blockIdx.x == 256) {
        const int t = threadIdx.x;
        if (t >= 128) return;
        const int d = t >> 4;
        const int c = t & 15;

        const float* p = partials + (d * CLS + c) * KCHUNK;
        float le = 0.f;
#pragma unroll
        for (int k = 0; k < KCHUNK; ++k) le += p[k];

        float cnt = 0.f;
        for (int b = 0; b < Bn; ++b) cnt += (labels[b] == c) ? 1.f : 0.f;
        const float xw = X_weights[c] + cnt;

        const float sig = sigmas[c], ssq = sig * sig;
        const float ta  = tao[d],    tsq = ta * ta;
        const float den = tsq + ssq;

        const float term1 = ssq / (den * den);
        const float term2 = ssq * le;
        const float term3 = (2.0f * (float)CHW) * (tsq * tsq - ssq * ssq) / xw;

        float v = term1 * (term2 + term3);
        v += __shfl_xor(v, 8);
        v += __shfl_xor(v, 4);
        v += __shfl_xor(v, 2);
        v += __shfl_xor(v, 1);
        if (c == 0) loss_out[d] = v * (1.0f / 16.0f);
        return;
    }

    // ---- kD path ----
    const int e0 = blockIdx.x * 64;       // element-chunk base, [0, CHW)
    const int t  = threadIdx.x;

    __shared__ float sh_mt[CLS][64];
    __shared__ float sh_lm[CLS][64];
    __shared__ float sh_y0[CLS][64];
    __shared__ float sh_y1[CLS][64];

    {   // stage: 256 threads x 1 float4 per array = [16][64] each
        const int c   = t >> 4;            // [0,16)
        const int el4 = (t & 15) << 2;     // [0,64) step 4
        st4(&sh_mt[c][el4], ld4(means_theta + c * CHW  + e0 + el4));
        st4(&sh_lm[c][el4], ld4(lmm         + c * CHW  + e0 + el4));
        st4(&sh_y0[c][el4], ld4(xy_out      + c * CHW2 + e0 + el4));
        st4(&sh_y1[c][el4], ld4(xy_out      + c * CHW2 + CHW + e0 + el4));
    }

    const float w0 = weight[0], w1w = weight[1], w2 = weight[2];
    const float w0sq = w0 * w0, w1sq = w1w * w1w, w2sq = w2 * w2;

    __syncthreads();

    // per wave: el = lane, b = k*4 + waveid  (covers all 32 b over 8 iters)
#pragma unroll 4
    for (int k = 0; k < 8; ++k) {
        const int w  = k * 256 + t;
        const int b  = w >> 6;             // [0,32)
        const int el = w & 63;             // = lane

        const float* xb = x + b * CHW4 + e0 + el;
        const float xt0 = xb[0];
        const float xt1 = xb[CHW];
        const float xx0 = xb[CHW2];
        const float xx1 = xb[CHW2 + CHW];
        const float lx  = __logf(xt1);

        float m = __builtin_inff();
#pragma unroll
        for (int c = 0; c < CLS; ++c) {
            const float dr = fabsf(xt0 - sh_mt[c][el]);
            const float da = fabsf(lx  - sh_lm[c][el]);
            const float d0 = xx0 - sh_y0[c][el];
            const float d1 = xx1 - sh_y1[c][el];
            m = fminf(m, w0sq * dr + w1sq * da + w2sq * (d0 * d0 + d1 * d1));
        }
        out[b * CHW + e0 + el] = m;
    }
}

// ---------------------------------------------------------------------------
extern "C" void kernel_launch(void* const* d_in, const int* in_sizes, int n_in,
                              void* d_out, int out_size, void* d_ws, size_t ws_size,
                              hipStream_t stream)
{
    const float* x         = (const float*)d_in[0];
    const int*   labels    = (const int*)  d_in[1];
    const float* X_LEs     = (const float*)d_in[2];
    const float* X_LEs_xy  = (const float*)d_in[3];
    const float* X_weights = (const float*)d_in[4];
    const float* sigmas    = (const float*)d_in[5];
    const float* w1        = (const float*)d_in[6];
    const float* miu       = (const float*)d_in[7];
    const float* tao       = (const float*)d_in[8];
    const float* weight    = (const float*)d_in[9];

    float* ws          = (float*)d_ws;
    float* xle_out     = ws;                      // 524288 floats
    float* xy_out      = ws + 524288;             // 524288
    float* means_theta = ws + 1048576;            // 262144
    float* lmm         = ws + 1310720;            // 262144
    float* partials    = ws + 1572864;            // 8192 (8*16*64)
    float* lm0a        = ws + 1581056;            // 131072
    float* lm1a        = ws + 1712128;            // 131072
    float* lm1ea       = ws + 1843200;            // 131072

    float* out  = (float*)d_out;       // 524288
    float* loss = out + Bn * CHW;      // 8

    hipLaunchKernelGGL(k1, dim3(512 + 128), dim3(256), 0, stream,
                       x, labels, X_LEs, X_LEs_xy, X_weights, miu,
                       xle_out, xy_out, lm0a, lm1a, lm1ea);
    hipLaunchKernelGGL(k2, dim3(CLS * KCHUNK), dim3(256), 0, stream,
                       xle_out, miu, sigmas, tao, w1, lm0a, lm1a, lm1ea,
                       means_theta, lmm, partials);
    hipLaunchKernelGGL(k3, dim3(256 + 1), dim3(256), 0, stream,
                       x, weight, means_theta, lmm, xy_out,
                       labels, X_weights, sigmas, tao, partials,
                       out, loss);
}